// Round 2
// baseline (15559.814 us; speedup 1.0000x reference)
//
#include <hip/hip_runtime.h>
#include <math.h>

#define EPSN 1e-5f
#define BATCH 8
#define NCH 64
#define XROW 8192
#define L0IN 8128
#define L1P1 4058
#define LOUTP1 3968
#define WLEN 194
#define NSTEP 32
#define OUTROW 4000

__device__ __forceinline__ float gelu_f(float x){
    float x3 = x*x*x;
    return 0.5f*x*(1.0f + tanhf(0.7978845608028654f*(x + 0.044715f*x3)));
}

// normalize raw value v given raw sums (sum, sumsq), invN, then scale/bias, then gelu
__device__ __forceinline__ float bn_gelu(float v, float sum, float sumsq, float invN, float s, float b){
    float m = sum*invN;
    float var = sumsq*invN - m*m;
    float rs = rsqrtf(var + EPSN);
    return gelu_f((v - m)*rs*s + b);
}

// ---------------- scalar stats (1-channel input), single block ----------------
__global__ void k_stats_scalar(const float* __restrict__ in, int bstride, int T, float* __restrict__ st){
    __shared__ float red[2048];
    int tid = threadIdx.x;
    float s = 0.f, sq = 0.f;
    int N = BATCH*T;
    for (int idx = tid; idx < N; idx += 1024){
        int b = idx / T, t = idx % T;
        float v = in[b*bstride + t];
        s += v; sq += v*v;
    }
    red[tid] = s; red[1024+tid] = sq;
    __syncthreads();
    for (int w = 512; w > 0; w >>= 1){
        if (tid < w){ red[tid] += red[tid+w]; red[1024+tid] += red[1024+tid+w]; }
        __syncthreads();
    }
    if (tid == 0){ st[0] = red[0]; st[1] = red[1024]; }
}

// ---------------- conv k=14 stride=2, 1ch input with analytic layer_in bn+gelu ----------------
__global__ void k_conv0(const float* __restrict__ in, int bstride, int Lin, int Lout,
                        const float* __restrict__ stX,
                        const float* __restrict__ w_in, const float* __restrict__ s_in, const float* __restrict__ b_in,
                        const float* __restrict__ w0,
                        float* __restrict__ out, float* __restrict__ stOut){
    __shared__ float lds[64*45];
    __shared__ float red[512];
    int b = blockIdx.y;
    int t0 = blockIdx.x * 16;
    int tid = threadIdx.x;
    int co = tid & 63, tg = tid >> 6;
    float invNx = 1.0f/(float)(BATCH*Lin);
    float mx = stX[0]*invNx;
    float vx = stX[1]*invNx - mx*mx;
    for (int idx = tid; idx < 44*64; idx += 256){
        int p = idx >> 6; int ci = idx & 63;
        int gp = 2*t0 + p;
        float val = 0.f;
        if (gp < Lin){
            float wc = w_in[ci];
            float raw = in[b*bstride + gp] * wc;
            float var = vx*wc*wc;
            float rs = rsqrtf(var + EPSN);
            val = gelu_f((raw - mx*wc)*rs*s_in[ci] + b_in[ci]);
        }
        lds[ci*45 + p] = val;
    }
    __syncthreads();
    float acc[4] = {0.f,0.f,0.f,0.f};
    for (int ci = 0; ci < 64; ++ci){
        float r[20];
        #pragma unroll
        for (int q = 0; q < 20; ++q) r[q] = lds[ci*45 + 8*tg + q];
        #pragma unroll
        for (int k = 0; k < 14; ++k){
            float w = w0[(k*64+ci)*64 + co];
            #pragma unroll
            for (int j = 0; j < 4; ++j) acc[j] = fmaf(r[2*j+k], w, acc[j]);
        }
    }
    float s = 0.f, sq = 0.f;
    #pragma unroll
    for (int j = 0; j < 4; ++j){
        int t = t0 + tg*4 + j;
        if (t < Lout){
            out[(b*Lout + t)*64 + co] = acc[j];
            s += acc[j]; sq += acc[j]*acc[j];
        }
    }
    red[tid] = s; red[256+tid] = sq;
    __syncthreads();
    if (tg == 0){
        float S  = red[co] + red[co+64] + red[co+128] + red[co+192];
        float SQ = red[256+co] + red[256+co+64] + red[256+co+128] + red[256+co+192];
        atomicAdd(&stOut[2*co],   S);
        atomicAdd(&stOut[2*co+1], SQ);
    }
}

// ---------------- conv k=7 stride=1, input = g(P) applied in LDS stage ----------------
__global__ void k_conv7(const float* __restrict__ P, int LP,
                        const float* __restrict__ stP, const float* __restrict__ s2, const float* __restrict__ b2,
                        const float* __restrict__ w,
                        float* __restrict__ Q, int LQ, float* __restrict__ stQ){
    __shared__ float lds[64*23];
    __shared__ float red[512];
    int b = blockIdx.y;
    int t0 = blockIdx.x * 16;
    int tid = threadIdx.x;
    int co = tid & 63, tg = tid >> 6;
    float invNp = 1.0f/(float)(BATCH*LP);
    for (int idx = tid; idx < 22*64; idx += 256){
        int p = idx >> 6; int ci = idx & 63;
        int gt = t0 + p;
        float val = 0.f;
        if (gt < LP){
            float raw = P[(b*LP + gt)*64 + ci];
            val = bn_gelu(raw, stP[2*ci], stP[2*ci+1], invNp, s2[ci], b2[ci]);
        }
        lds[ci*23 + p] = val;
    }
    __syncthreads();
    float acc[4] = {0.f,0.f,0.f,0.f};
    for (int ci = 0; ci < 64; ++ci){
        float r[10];
        #pragma unroll
        for (int q = 0; q < 10; ++q) r[q] = lds[ci*23 + tg*4 + q];
        #pragma unroll
        for (int k = 0; k < 7; ++k){
            float wv = w[(k*64+ci)*64 + co];
            #pragma unroll
            for (int j = 0; j < 4; ++j) acc[j] = fmaf(r[j+k], wv, acc[j]);
        }
    }
    float s = 0.f, sq = 0.f;
    #pragma unroll
    for (int j = 0; j < 4; ++j){
        int t = t0 + tg*4 + j;
        if (t < LQ){
            Q[(b*LQ + t)*64 + co] = acc[j];
            s += acc[j]; sq += acc[j]*acc[j];
        }
    }
    red[tid] = s; red[256+tid] = sq;
    __syncthreads();
    if (tg == 0){
        float S  = red[co] + red[co+64] + red[co+128] + red[co+192];
        float SQ = red[256+co] + red[256+co+64] + red[256+co+128] + red[256+co+192];
        atomicAdd(&stQ[2*co],   S);
        atomicAdd(&stQ[2*co+1], SQ);
    }
}

// ---------------- elementwise: Q = gelu(bn1(Q_raw)) [+ g(P[t+6])*wsk], stats of result ----------------
__global__ void k_elem(float* __restrict__ Q, int LQ,
                       const float* __restrict__ stQ, const float* __restrict__ s1, const float* __restrict__ b1,
                       const float* __restrict__ P, int LP,
                       const float* __restrict__ stP, const float* __restrict__ s2, const float* __restrict__ b2,
                       const float* __restrict__ wsk,
                       float* __restrict__ stOut){
    __shared__ float red[512];
    int tid = threadIdx.x;
    int c = tid & 63;
    int N = BATCH*LQ*64;
    int stride = gridDim.x*blockDim.x;
    float invNq = 1.0f/(float)(BATCH*LQ);
    float invNp = P ? 1.0f/(float)(BATCH*LP) : 0.f;
    float s = 0.f, sq = 0.f;
    for (int idx = blockIdx.x*blockDim.x + tid; idx < N; idx += stride){
        float v = Q[idx];
        float y = bn_gelu(v, stQ[2*c], stQ[2*c+1], invNq, s1[c], b1[c]);
        if (P){
            int bt = idx >> 6;
            int t  = bt % LQ;
            int bb = bt / LQ;
            float pv = P[(bb*LP + t + 6)*64 + c];
            y += bn_gelu(pv, stP[2*c], stP[2*c+1], invNp, s2[c], b2[c]) * wsk[c];
        }
        Q[idx] = y;
        s += y; sq += y*y;
    }
    red[tid] = s; red[256+tid] = sq;
    __syncthreads();
    if (tid < 64){
        float S  = red[c] + red[c+64] + red[c+128] + red[c+192];
        float SQ = red[256+c] + red[256+c+64] + red[256+c+128] + red[256+c+192];
        atomicAdd(&stOut[2*c],   S);
        atomicAdd(&stOut[2*c+1], SQ);
    }
}

// ---------------- output conv (64->1) with scalar stats ----------------
__global__ void k_convout(const float* __restrict__ P, int LQ,
                          const float* __restrict__ stP, const float* __restrict__ s2, const float* __restrict__ b2,
                          const float* __restrict__ w_out,
                          float* __restrict__ o_raw, float* __restrict__ stOut){
    __shared__ float red[8];
    int tid = threadIdx.x;
    int c = tid & 63, tq = tid >> 6;
    int M = BATCH*LQ;
    float invNp = 1.0f/(float)(BATCH*LQ);
    float myw = w_out[c];
    float ms = stP[2*c], msq = stP[2*c+1], ss = s2[c], bb = b2[c];
    float ls = 0.f, lq = 0.f;
    for (int m = blockIdx.x*4 + tq; m < M; m += gridDim.x*4){
        float pv = P[m*64 + c];
        float val = bn_gelu(pv, ms, msq, invNp, ss, bb) * myw;
        #pragma unroll
        for (int off = 32; off > 0; off >>= 1) val += __shfl_down(val, off, 64);
        if (c == 0){ o_raw[m] = val; ls += val; lq += val*val; }
    }
    if (c == 0){ red[tq] = ls; red[4+tq] = lq; }
    __syncthreads();
    if (tid == 0){
        atomicAdd(&stOut[0], red[0]+red[1]+red[2]+red[3]);
        atomicAdd(&stOut[1], red[4]+red[5]+red[6]+red[7]);
    }
}

// ---------------- phase-1 finalize: z0 -> d_out ----------------
__global__ void k_finalize1(const float* __restrict__ o_raw, const float* __restrict__ st,
                            const float* __restrict__ s_out, const float* __restrict__ b_out,
                            float* __restrict__ out){
    float invN = 1.0f/(float)(BATCH*LOUTP1);
    float m = st[0]*invN;
    float var = st[1]*invN - m*m;
    float rs = rsqrtf(var + EPSN);
    float so = s_out[0], bo = b_out[0];
    int N = BATCH*LOUTP1;
    for (int idx = blockIdx.x*blockDim.x + threadIdx.x; idx < N; idx += gridDim.x*blockDim.x){
        int b = idx / LOUTP1, t = idx % LOUTP1;
        out[b*OUTROW + t] = (o_raw[idx]-m)*rs*so + bo;
    }
}

// ---------------- init rolling window W1 = [x[7936:8128], x[8128], z0_last]; + its stats ----------------
__global__ void k_initW(const float* __restrict__ x, const float* __restrict__ out,
                        float* __restrict__ W, float* __restrict__ stX){
    __shared__ float red[512];
    int tid = threadIdx.x;
    float s = 0.f, sq = 0.f;
    for (int idx = tid; idx < BATCH*WLEN; idx += 256){
        int b = idx / WLEN, j = idx % WLEN;
        float v;
        if (j < 192)       v = x[b*XROW + 7936 + j];
        else if (j == 192) v = x[b*XROW + 8128];
        else               v = out[b*OUTROW + 3967];
        W[b*WLEN + j] = v;
        s += v; sq += v*v;
    }
    red[tid] = s; red[256+tid] = sq;
    __syncthreads();
    for (int w = 128; w > 0; w >>= 1){
        if (tid < w){ red[tid] += red[tid+w]; red[256+tid] += red[256+tid+w]; }
        __syncthreads();
    }
    if (tid == 0){ stX[0] = red[0]; stX[1] = red[256]; }
}

// ---------------- per-step finalize: out sample, build next window + its stats ----------------
__global__ void k_finalize2(const float* __restrict__ o_raw, const float* __restrict__ st,
                            const float* __restrict__ s_out, const float* __restrict__ b_out,
                            const float* __restrict__ x, const float* __restrict__ Wcur,
                            float* __restrict__ Wnext, float* __restrict__ out, int k,
                            float* __restrict__ stX){
    __shared__ float red[512];
    __shared__ float outv[8];
    int tid = threadIdx.x;
    float m = st[0]*0.125f;
    float var = st[1]*0.125f - m*m;
    float rs = rsqrtf(var + EPSN);
    if (tid < 8){
        float v = (o_raw[tid]-m)*rs*s_out[0] + b_out[0];
        outv[tid] = v;
        out[tid*OUTROW + 3968 + k] = v;
    }
    __syncthreads();
    if (k >= NSTEP-1) return;
    float s = 0.f, sq = 0.f;
    for (int idx = tid; idx < BATCH*WLEN; idx += 256){
        int b = idx / WLEN, j = idx % WLEN;
        float v;
        if (j < 192)       v = Wcur[b*WLEN + j + 2];
        else if (j == 192) v = x[b*XROW + L0IN + 2*(k+1)];
        else               v = outv[b];
        Wnext[b*WLEN + j] = v;
        s += v; sq += v*v;
    }
    red[tid] = s; red[256+tid] = sq;
    __syncthreads();
    for (int w = 128; w > 0; w >>= 1){
        if (tid < w){ red[tid] += red[tid+w]; red[256+tid] += red[256+tid+w]; }
        __syncthreads();
    }
    if (tid == 0){ stX[0] = red[0]; stX[1] = red[256]; }
}

static inline int imin(int a, int b){ return a < b ? a : b; }

extern "C" void kernel_launch(void* const* d_in, const int* in_sizes, int n_in,
                              void* d_out, int out_size, void* d_ws, size_t ws_size,
                              hipStream_t stream){
    const float* x      = (const float*)d_in[0];
    const float* w_in   = (const float*)d_in[1];
    const float* w0     = (const float*)d_in[2];
    const float* w_conv = (const float*)d_in[3];
    const float* w_skip = (const float*)d_in[4];
    const float* w_out  = (const float*)d_in[5];
    const float* s_in   = (const float*)d_in[6];
    const float* b_in   = (const float*)d_in[7];
    const float* s0a    = (const float*)d_in[8];
    const float* b0a    = (const float*)d_in[9];
    const float* s0b    = (const float*)d_in[10];
    const float* b0b    = (const float*)d_in[11];
    const float* sa     = (const float*)d_in[12];
    const float* ba     = (const float*)d_in[13];
    const float* sb     = (const float*)d_in[14];
    const float* bb     = (const float*)d_in[15];
    const float* s_out  = (const float*)d_in[16];
    const float* b_out  = (const float*)d_in[17];
    float* out = (float*)d_out;

    float* ws = (float*)d_ws;
    size_t off = 0;
    float* buf0  = ws + off; off += (size_t)BATCH*L1P1*64;
    float* buf1  = ws + off; off += (size_t)BATCH*L1P1*64;
    float* o_raw = ws + off; off += BATCH*LOUTP1;
    float* W0    = ws + off; off += BATCH*WLEN;
    float* W1    = ws + off; off += BATCH*WLEN;
    float* stats = ws + off; off += 4100;
    // stats layout: [0..1]=STX, [2..129]=STB, [130..257]=STC,
    // [258+256i .. ]=STY(i), +128 =STY2(i), [4098..4099]=STOUT
    float* STX = stats;
    float* STB = stats + 2;
    float* STC = stats + 130;
    float* STOUT = stats + 4098;

    // generic stack runner; In1 is the 1-channel input (bstride elems per batch row)
    auto run_stack = [&](const float* In1, int bstride, int Lin, int* finalLen, const float** finalBuf,
                         const float** fstP, const float** fs2, const float** fb2){
        int Lc = (Lin - 14)/2 + 1;
        hipMemsetAsync((void*)STB, 0, (4100-2)*sizeof(float), stream);
        k_conv0<<<dim3((Lc+15)/16, BATCH), 256, 0, stream>>>(In1, bstride, Lin, Lc, STX,
                                                             w_in, s_in, b_in, w0, buf0, STB);
        {
            int N = BATCH*Lc*64;
            int g = imin((N+255)/256, 2048);
            k_elem<<<g, 256, 0, stream>>>(buf0, Lc, STB, s0a, b0a,
                                          nullptr, 0, nullptr, nullptr, nullptr, nullptr, STC);
        }
        float* A = buf0; float* Bf = buf1;
        const float* stP = STC; const float* cs2 = s0b; const float* cb2 = b0b;
        int LP = Lc;
        for (int i = 0; i < 15; ++i){
            int LQ = LP - 6;
            float* stY  = stats + 258 + i*256;
            float* stY2 = stY + 128;
            k_conv7<<<dim3((LQ+15)/16, BATCH), 256, 0, stream>>>(A, LP, stP, cs2, cb2,
                                                                 w_conv + (size_t)i*7*64*64, Bf, LQ, stY);
            int N = BATCH*LQ*64;
            int g = imin((N+255)/256, 2048);
            k_elem<<<g, 256, 0, stream>>>(Bf, LQ, stY, sa + 64*i, ba + 64*i,
                                          A, LP, stP, cs2, cb2, w_skip + 64*i, stY2);
            stP = stY2; cs2 = sb + 64*i; cb2 = bb + 64*i;
            float* tmp = A; A = Bf; Bf = tmp;
            LP = LQ;
        }
        int g = imin((BATCH*LP+3)/4, 512);
        k_convout<<<g, 256, 0, stream>>>(A, LP, stP, cs2, cb2, w_out, o_raw, STOUT);
        *finalLen = LP; *finalBuf = A; *fstP = stP; *fs2 = cs2; *fb2 = cb2;
    };

    // -------- phase 1 --------
    hipMemsetAsync((void*)STX, 0, 2*sizeof(float), stream);
    k_stats_scalar<<<1, 1024, 0, stream>>>(x, XROW, L0IN, STX);
    int fl; const float* fb; const float* fst; const float* fs2; const float* fb2;
    run_stack(x, XROW, L0IN, &fl, &fb, &fst, &fs2, &fb2);
    k_finalize1<<<imin((BATCH*LOUTP1+255)/256, 512), 256, 0, stream>>>(o_raw, STOUT, s_out, b_out, out);
    k_initW<<<1, 256, 0, stream>>>(x, out, W0, STX);

    // -------- phase 2: 32 serial steps --------
    for (int k = 0; k < NSTEP; ++k){
        float* Wc = (k & 1) ? W1 : W0;
        float* Wn = (k & 1) ? W0 : W1;
        run_stack(Wc, WLEN, WLEN, &fl, &fb, &fst, &fs2, &fb2);
        k_finalize2<<<1, 256, 0, stream>>>(o_raw, STOUT, s_out, b_out, x, Wc, Wn, out, k, STX);
    }
}